// Round 1
// 532.480 us; speedup vs baseline: 1.0122x; 1.0122x over previous
//
#include <hip/hip_runtime.h>
#include <hip/hip_bf16.h>
#include <math.h>

typedef __bf16 bf16;
typedef bf16 bf16x2 __attribute__((ext_vector_type(2)));
typedef bf16 bf16x4 __attribute__((ext_vector_type(4)));
typedef bf16 bf16x8 __attribute__((ext_vector_type(8)));
typedef float f32x4 __attribute__((ext_vector_type(4)));

#define T_TOK 4096
#define DDIM  768
#define HDIM  2688
#define NEXP  8
#define RMAX  9216            // max padded pair rows (8192 + 8*127 rounded up)
#define NMT   (RMAX / 128)    // 72 max mtiles
#define NT1   (HDIM / 64)     // 42
#define NT2   (DDIM / 128)    // 6
#define KHALF (HDIM / 2)      // 1344

__device__ __forceinline__ void async_copy16(const void* g, void* l) {
    __builtin_amdgcn_global_load_lds(
        (__attribute__((address_space(1))) void*)g,
        (__attribute__((address_space(3))) void*)l,
        16, 0, 0);
}

// ---------------- Router ----------------
__global__ void router_kernel(const float* __restrict__ x,
                              const float* __restrict__ gate_w,
                              const float* __restrict__ ebias,
                              int* __restrict__ ctrl,
                              int* __restrict__ tok_e,
                              float* __restrict__ tok_w,
                              float* __restrict__ zloss) {
    __shared__ float gw[NEXP * DDIM];
    int tid = threadIdx.x;
    for (int i = tid; i < NEXP * DDIM / 4; i += 256)
        ((float4*)gw)[i] = ((const float4*)gate_w)[i];
    __syncthreads();

    int wv = tid >> 6, lane = tid & 63;
    int t = blockIdx.x * 4 + wv;
    const float* xr = x + (size_t)t * DDIM;

    float4 xv[3];
#pragma unroll
    for (int j = 0; j < 3; ++j) xv[j] = ((const float4*)xr)[j * 64 + lane];

    float acc[NEXP];
#pragma unroll
    for (int e = 0; e < NEXP; ++e) {
        float a = 0.f;
#pragma unroll
        for (int j = 0; j < 3; ++j) {
            float4 w = ((const float4*)(gw + e * DDIM))[j * 64 + lane];
            a += xv[j].x * w.x + xv[j].y * w.y + xv[j].z * w.z + xv[j].w * w.w;
        }
        acc[e] = a;
    }
#pragma unroll
    for (int e = 0; e < NEXP; ++e) {
#pragma unroll
        for (int off = 32; off > 0; off >>= 1) acc[e] += __shfl_xor(acc[e], off);
    }

    if (lane == 0) {
        float b[NEXP];
#pragma unroll
        for (int e = 0; e < NEXP; ++e) b[e] = acc[e] + ebias[e];
        int i0 = 0;
#pragma unroll
        for (int e = 1; e < NEXP; ++e) if (b[e] > b[i0]) i0 = e;
        int i1 = (i0 == 0) ? 1 : 0;
        float b1 = b[i1];
#pragma unroll
        for (int e = 0; e < NEXP; ++e) if (e != i0 && b[e] > b1) { b1 = b[e]; i1 = e; }

        float l0 = acc[i0], l1 = acc[i1];
        float mx = fmaxf(l0, l1);
        float e0 = __expf(l0 - mx), e1 = __expf(l1 - mx);
        float inv = 1.f / (e0 + e1);
        tok_e[t * 2 + 0] = i0;
        tok_e[t * 2 + 1] = i1;
        tok_w[t * 2 + 0] = e0 * inv;
        tok_w[t * 2 + 1] = e1 * inv;
        atomicAdd(&ctrl[i0], 1);
        atomicAdd(&ctrl[i1], 1);

        float m8 = acc[0];
#pragma unroll
        for (int e = 1; e < NEXP; ++e) m8 = fmaxf(m8, acc[e]);
        float s = 0.f;
#pragma unroll
        for (int e = 0; e < NEXP; ++e) s += __expf(acc[e] - m8);
        float lse = m8 + __logf(s);
        atomicAdd(zloss, (1e-5f / (float)T_TOK) * lse * lse);
    }
}

__global__ void offsets_kernel(int* ctrl) {
    if (threadIdx.x == 0 && blockIdx.x == 0) {
        int off = 0;
        for (int e = 0; e < NEXP; ++e) {
            ctrl[16 + e] = off;
            off += (ctrl[e] + 127) & ~127;
        }
        ctrl[16 + NEXP] = off;
    }
}

__global__ void scatter_kernel(int* __restrict__ ctrl,
                               const int* __restrict__ tok_e,
                               const float* __restrict__ tok_w,
                               int* __restrict__ pair_tok,
                               int* __restrict__ tok_pos) {
    int t = blockIdx.x * 256 + threadIdx.x;
    if (t >= T_TOK) return;
#pragma unroll
    for (int k = 0; k < 2; ++k) {
        int e = tok_e[t * 2 + k];
        int pos = ctrl[16 + e] + atomicAdd(&ctrl[8 + e], 1);
        pair_tok[pos] = t;
        tok_pos[t * 2 + k] = pos;
    }
}

__global__ void gather_kernel(const float* __restrict__ x,
                              const int* __restrict__ ctrl,
                              const int* __restrict__ pair_tok,
                              bf16* __restrict__ Xg) {
    int r = blockIdx.x;
    int tid = threadIdx.x;  // 192 threads, 4 floats each
    const int* offs = ctrl + 16;
    int total = offs[8];
    int tok = -1;
    if (r < total) {
        int e = 0;
#pragma unroll
        for (int i = 1; i < NEXP; ++i) if (r >= offs[i]) e = i;
        if (r - offs[e] < ctrl[e]) tok = pair_tok[r];
    }
    bf16x4 o;
    if (tok >= 0) {
        float4 v = *(const float4*)(x + (size_t)tok * DDIM + tid * 4);
        o.x = (bf16)v.x; o.y = (bf16)v.y; o.z = (bf16)v.z; o.w = (bf16)v.w;
    } else {
        o.x = (bf16)0.f; o.y = (bf16)0.f; o.z = (bf16)0.f; o.w = (bf16)0.f;
    }
    *(bf16x4*)(Xg + (size_t)r * DDIM + tid * 4) = o;
}

// ---------------- Weight transpose fp32->bf16 ----------------
// float4 loads, XOR-swizzled LDS tile (bank-balanced column reads), bf16x8 stores.
__global__ void transpose_kernel(const float* __restrict__ wgp,
                                 const float* __restrict__ wup,
                                 const float* __restrict__ wdp,
                                 bf16* __restrict__ WgT,
                                 bf16* __restrict__ WuT,
                                 bf16* __restrict__ WdT) {
    __shared__ float tile[64 * 64];
    int m = blockIdx.y;
    int kind = m >> 3, e = m & 7;
    const float* src; bf16* dst; int R, C;
    if (kind == 0)      { src = wgp + (size_t)e * DDIM * HDIM; dst = WgT + (size_t)e * HDIM * DDIM; R = DDIM; C = HDIM; }
    else if (kind == 1) { src = wup + (size_t)e * DDIM * HDIM; dst = WuT + (size_t)e * HDIM * DDIM; R = DDIM; C = HDIM; }
    else                { src = wdp + (size_t)e * HDIM * DDIM; dst = WdT + (size_t)e * DDIM * HDIM; R = HDIM; C = DDIM; }

    int nR = R >> 6;
    int t = blockIdx.x;
    int tr = t % nR, tc = t / nR;
    int r0 = tr << 6, c0 = tc << 6;
    int tid = threadIdx.x;

    // load 64x64 fp32 tile: element (rr, c) stored at tile[rr*64 + ((c>>2)^((rr>>3)&3))*4 + (c&3)]
#pragma unroll
    for (int i = 0; i < 4; ++i) {
        int idx = i * 256 + tid;
        int rr = idx >> 4, c4 = idx & 15;
        int cs = c4 ^ ((rr >> 3) & 3);
        float4 v = *(const float4*)(src + (size_t)(r0 + rr) * C + c0 + c4 * 4);
        *(float4*)&tile[rr * 64 + cs * 4] = v;
    }
    __syncthreads();

    // store transposed: each thread writes bf16x8 (8 src-rows for one src-col)
#pragma unroll
    for (int i = 0; i < 2; ++i) {
        int idx = i * 256 + tid;
        int cc = idx >> 3, rp0 = (idx & 7) * 8;
        bf16x8 o;
#pragma unroll
        for (int j = 0; j < 8; ++j) {
            int r = rp0 + j;
            o[j] = (bf16)tile[r * 64 + (((cc >> 2) ^ ((r >> 3) & 3)) << 2) + (cc & 3)];
        }
        *(bf16x8*)(dst + (size_t)(c0 + cc) * R + r0 + rp0) = o;
    }
}

// ---------------- GEMM1: G = silu(Xg@Wg) * (Xg@Wu) ----------------
// grid: gm*NT1 + nt; tile 128 rows x 64 cols (gate & up); BK=32, dbuf, swizzled LDS.
__launch_bounds__(256)
__global__ void gemm1_kernel(const bf16* __restrict__ Xg,
                             const bf16* __restrict__ WgT,
                             const bf16* __restrict__ WuT,
                             const int* __restrict__ ctrl,
                             bf16* __restrict__ G) {
    int id = blockIdx.x;
    int gm = id / NT1, nt = id % NT1;
    const int* offs = ctrl + 16;
    int row0 = gm * 128;
    if (row0 >= offs[NEXP]) return;
    int e = 0;
#pragma unroll
    for (int i = 1; i < NEXP; ++i) if (row0 >= offs[i]) e = i;
    int n0 = nt * 64;

    // flat LDS: sA 2x(128*32)=8192, sBg 2x(64*32)=4096, sBu 4096 -> 16384 elems (32 KB)
    __shared__ __align__(16) bf16 smem[16384];
    bf16* sA  = smem;
    bf16* sBg = smem + 8192;
    bf16* sBu = smem + 12288;

    int tid = threadIdx.x;
    int wv = tid >> 6, lane = tid & 63;
    int wm = wv & 1, wn = wv >> 1;
    int quad = lane >> 4, lm = lane & 15;

    // staging: lane (arow, aseg) sources swizzled k-chunk aseg^((arow>>1)&3)
    int arow = tid >> 2, aseg = tid & 3;
    int kc = (aseg ^ ((arow >> 1) & 3)) * 8;
    size_t aoff = (size_t)arow * DDIM + kc;

    const bf16* Ab = Xg + (size_t)row0 * DDIM + aoff;
    const bf16* A2 = Ab + (size_t)64 * DDIM;
    const bf16* Bg = WgT + ((size_t)e * HDIM + n0) * DDIM + aoff;
    const bf16* Bu = WuT + ((size_t)e * HDIM + n0) * DDIM + aoff;

    bf16* dA  = sA + (size_t)tid * 8;
    bf16* dA2 = dA + 2048;
    bf16* dBg = sBg + (size_t)tid * 8;
    bf16* dBu = sBu + (size_t)tid * 8;

    // fragment read bases (swizzled): row stride 32 elts, chunk quad^((lm>>1)&3)
    int swq = quad ^ ((lm >> 1) & 3);
    const bf16* fa = sA + (wm * 64 + lm) * 32 + swq * 8;
    const bf16* fg = sBg + (wn * 32 + lm) * 32 + swq * 8;
    const bf16* fu = sBu + (wn * 32 + lm) * 32 + swq * 8;

    f32x4 accg[4][2], accu[4][2];
#pragma unroll
    for (int mi = 0; mi < 4; ++mi)
#pragma unroll
        for (int ni = 0; ni < 2; ++ni) { accg[mi][ni] = 0.f; accu[mi][ni] = 0.f; }

    // prologue stage into buf 0
    async_copy16(Ab, dA);
    async_copy16(A2, dA2);
    async_copy16(Bg, dBg);
    async_copy16(Bu, dBu);

    const int NK = DDIM / 32;  // 24
#pragma unroll
    for (int ks = 0; ks < NK; ++ks) {
        __syncthreads();
        if (ks + 1 < NK) {
            int kk = (ks + 1) * 32;
            int bo = ((ks + 1) & 1) ? 1 : 0;
            async_copy16(Ab + kk, dA + bo * 4096);
            async_copy16(A2 + kk, dA2 + bo * 4096);
            async_copy16(Bg + kk, dBg + bo * 2048);
            async_copy16(Bu + kk, dBu + bo * 2048);
        }
        int buf = ks & 1;
        bf16x8 af[4], bg[2], bu[2];
#pragma unroll
        for (int mi = 0; mi < 4; ++mi)
            af[mi] = *(const bf16x8*)(fa + buf * 4096 + mi * 16 * 32);
#pragma unroll
        for (int ni = 0; ni < 2; ++ni) {
            bg[ni] = *(const bf16x8*)(fg + buf * 2048 + ni * 16 * 32);
            bu[ni] = *(const bf16x8*)(fu + buf * 2048 + ni * 16 * 32);
        }
#pragma unroll
        for (int mi = 0; mi < 4; ++mi)
#pragma unroll
            for (int ni = 0; ni < 2; ++ni) {
                accg[mi][ni] = __builtin_amdgcn_mfma_f32_16x16x32_bf16(af[mi], bg[ni], accg[mi][ni], 0, 0, 0);
                accu[mi][ni] = __builtin_amdgcn_mfma_f32_16x16x32_bf16(af[mi], bu[ni], accu[mi][ni], 0, 0, 0);
            }
    }

    // epilogue: SwiGLU + LDS repack -> coalesced bf16x8 stores
    __syncthreads();   // all waves done reading staging LDS
#pragma unroll
    for (int mi = 0; mi < 4; ++mi)
#pragma unroll
        for (int ni = 0; ni < 2; ++ni)
#pragma unroll
            for (int r = 0; r < 4; ++r) {
                float gg = accg[mi][ni][r];
                float u = accu[mi][ni][r];
                float val = (gg / (1.f + __expf(-gg))) * u;
                int rl = wm * 64 + mi * 16 + quad * 4 + r;
                int c  = wn * 32 + ni * 16 + lm;
                smem[rl * 72 + c] = (bf16)val;   // stride 72 elems = 144B (16B-mult)
            }
    __syncthreads();
#pragma unroll
    for (int i = 0; i < 4; ++i) {
        int idx = (i * 256 + tid) * 8;
        int row = idx >> 6, c = idx & 63;
        bf16x8 v = *(const bf16x8*)(smem + row * 72 + c);
        *(bf16x8*)(G + (size_t)(row0 + row) * HDIM + n0 + c) = v;
    }
}

// ---------------- GEMM2: Y_s = G[:, s*1344:(s+1)*1344] @ Wd[s half], bf16 partials ----------------
__launch_bounds__(256)
__global__ void gemm2_kernel(const bf16* __restrict__ G,
                             const bf16* __restrict__ WdT,
                             const int* __restrict__ ctrl,
                             bf16* __restrict__ Ya,
                             bf16* __restrict__ Yb) {
    int id = blockIdx.x;
    int gm = id / (NT2 * 2);
    int r2 = id % (NT2 * 2);
    int nt = r2 >> 1, s = r2 & 1;
    const int* offs = ctrl + 16;
    int row0 = gm * 128;
    if (row0 >= offs[NEXP]) return;
    int e = 0;
#pragma unroll
    for (int i = 1; i < NEXP; ++i) if (row0 >= offs[i]) e = i;
    int n0 = nt * 128;

    __shared__ __align__(16) bf16 smem[16384];   // sA 2x4096 | sB 2x4096
    bf16* sA = smem;
    bf16* sB = smem + 8192;

    int tid = threadIdx.x;
    int wv = tid >> 6, lane = tid & 63;
    int wm = wv & 1, wn = wv >> 1;
    int quad = lane >> 4, lm = lane & 15;

    int arow = tid >> 2, aseg = tid & 3;
    int kc = (aseg ^ ((arow >> 1) & 3)) * 8;
    size_t aoff = (size_t)arow * HDIM + kc + s * KHALF;

    const bf16* Ab = G + (size_t)row0 * HDIM + aoff;
    const bf16* A2 = Ab + (size_t)64 * HDIM;
    const bf16* Bb = WdT + ((size_t)e * DDIM + n0) * HDIM + aoff;
    const bf16* B2 = Bb + (size_t)64 * HDIM;

    bf16* dA  = sA + (size_t)tid * 8;
    bf16* dA2 = dA + 2048;
    bf16* dB  = sB + (size_t)tid * 8;
    bf16* dB2 = dB + 2048;

    int swq = quad ^ ((lm >> 1) & 3);
    const bf16* fa = sA + (wm * 64 + lm) * 32 + swq * 8;
    const bf16* fb = sB + (wn * 64 + lm) * 32 + swq * 8;

    f32x4 acc[4][4];
#pragma unroll
    for (int mi = 0; mi < 4; ++mi)
#pragma unroll
        for (int ni = 0; ni < 4; ++ni) acc[mi][ni] = 0.f;

    async_copy16(Ab, dA);
    async_copy16(A2, dA2);
    async_copy16(Bb, dB);
    async_copy16(B2, dB2);

    const int NK = KHALF / 32;  // 42
#pragma unroll
    for (int ks = 0; ks < NK; ++ks) {
        __syncthreads();
        if (ks + 1 < NK) {
            int kk = (ks + 1) * 32;
            int bo = ((ks + 1) & 1) ? 1 : 0;
            async_copy16(Ab + kk, dA + bo * 4096);
            async_copy16(A2 + kk, dA2 + bo * 4096);
            async_copy16(Bb + kk, dB + bo * 4096);
            async_copy16(B2 + kk, dB2 + bo * 4096);
        }
        int buf = ks & 1;
        bf16x8 af[4], bb[4];
#pragma unroll
        for (int mi = 0; mi < 4; ++mi)
            af[mi] = *(const bf16x8*)(fa + buf * 4096 + mi * 16 * 32);
#pragma unroll
        for (int ni = 0; ni < 4; ++ni)
            bb[ni] = *(const bf16x8*)(fb + buf * 4096 + ni * 16 * 32);
#pragma unroll
        for (int mi = 0; mi < 4; ++mi)
#pragma unroll
            for (int ni = 0; ni < 4; ++ni)
                acc[mi][ni] = __builtin_amdgcn_mfma_f32_16x16x32_bf16(af[mi], bb[ni], acc[mi][ni], 0, 0, 0);
    }

    // epilogue: two rounds (ni pairs) of LDS repack -> coalesced bf16x8 stores
    bf16* Y = s ? Yb : Ya;
    __syncthreads();   // all waves done reading staging LDS
#pragma unroll
    for (int rr = 0; rr < 2; ++rr) {
#pragma unroll
        for (int mi = 0; mi < 4; ++mi)
#pragma unroll
            for (int nj = 0; nj < 2; ++nj) {
                int ni = rr * 2 + nj;
#pragma unroll
                for (int r = 0; r < 4; ++r) {
                    int rl = wm * 64 + mi * 16 + quad * 4 + r;
                    int c  = wn * 32 + nj * 16 + lm;
                    smem[rl * 72 + c] = (bf16)acc[mi][ni][r];
                }
            }
        __syncthreads();
#pragma unroll
        for (int i = 0; i < 4; ++i) {
            int idx = (i * 256 + tid) * 8;
            int row = idx >> 6, c = idx & 63;
            bf16x8 v = *(const bf16x8*)(smem + row * 72 + c);
            int col = n0 + ((c >> 5) << 6) + (c & 31) + rr * 32;
            *(bf16x8*)(Y + (size_t)(row0 + row) * DDIM + col) = v;
        }
        if (rr == 0) __syncthreads();
    }
}

// ---------------- Combine: out[t] = w0*(Ya[p0]+Yb[p0]) + w1*(Ya[p1]+Yb[p1]) ----------------
__global__ void combine_kernel(const bf16* __restrict__ Ya,
                               const bf16* __restrict__ Yb,
                               const int* __restrict__ tok_pos,
                               const float* __restrict__ tok_w,
                               float* __restrict__ out) {
    int t = blockIdx.x;
    int i = threadIdx.x;           // 192 threads x 4 cols
    int p0 = tok_pos[t * 2 + 0], p1 = tok_pos[t * 2 + 1];
    float w0 = tok_w[t * 2 + 0], w1 = tok_w[t * 2 + 1];
    bf16x4 a0 = *(const bf16x4*)(Ya + (size_t)p0 * DDIM + i * 4);
    bf16x4 b0 = *(const bf16x4*)(Yb + (size_t)p0 * DDIM + i * 4);
    bf16x4 a1 = *(const bf16x4*)(Ya + (size_t)p1 * DDIM + i * 4);
    bf16x4 b1 = *(const bf16x4*)(Yb + (size_t)p1 * DDIM + i * 4);
    float4 o;
    o.x = w0 * ((float)a0.x + (float)b0.x) + w1 * ((float)a1.x + (float)b1.x);
    o.y = w0 * ((float)a0.y + (float)b0.y) + w1 * ((float)a1.y + (float)b1.y);
    o.z = w0 * ((float)a0.z + (float)b0.z) + w1 * ((float)a1.z + (float)b1.z);
    o.w = w0 * ((float)a0.w + (float)b0.w) + w1 * ((float)a1.w + (float)b1.w);
    *(float4*)(out + (size_t)t * DDIM + i * 4) = o;
}

extern "C" void kernel_launch(void* const* d_in, const int* in_sizes, int n_in,
                              void* d_out, int out_size, void* d_ws, size_t ws_size,
                              hipStream_t stream) {
    const float* x      = (const float*)d_in[0];
    const float* gate_w = (const float*)d_in[1];
    const float* ebias  = (const float*)d_in[2];
    const float* wgp    = (const float*)d_in[3];
    const float* wup    = (const float*)d_in[4];
    const float* wdp    = (const float*)d_in[5];
    float* out = (float*)d_out;

    int*   ctrl     = (int*)d_ws;                          // 128 ints
    int*   tok_e    = ctrl + 128;                          // 2T
    float* tok_w    = (float*)(tok_e + 2 * T_TOK);         // 2T
    int*   pair_tok = (int*)(tok_w + 2 * T_TOK);           // RMAX
    int*   tok_pos  = pair_tok + RMAX;                     // 2T
    bf16*  Xg       = (bf16*)(tok_pos + 2 * T_TOK);        // RMAX*768 (reused as Ya)
    bf16*  Ya       = Xg;
    bf16*  Yb       = Xg + (size_t)RMAX * DDIM;            // RMAX*768
    bf16*  G        = Yb + (size_t)RMAX * DDIM;            // RMAX*2688
    bf16*  WgT      = G + (size_t)RMAX * HDIM;
    bf16*  WuT      = WgT + (size_t)NEXP * DDIM * HDIM;
    bf16*  WdT      = WuT + (size_t)NEXP * DDIM * HDIM;

    hipMemsetAsync(out + (size_t)T_TOK * DDIM, 0, sizeof(float), stream);  // z_loss
    hipMemsetAsync(d_ws, 0, 512, stream);                                  // ctrl

    router_kernel<<<T_TOK / 4, 256, 0, stream>>>(x, gate_w, ebias, ctrl, tok_e, tok_w,
                                                 out + (size_t)T_TOK * DDIM);
    offsets_kernel<<<1, 64, 0, stream>>>(ctrl);
    scatter_kernel<<<T_TOK / 256, 256, 0, stream>>>(ctrl, tok_e, tok_w, pair_tok, tok_pos);
    transpose_kernel<<<dim3(504, 24), 256, 0, stream>>>(wgp, wup, wdp, WgT, WuT, WdT);
    gather_kernel<<<RMAX, 192, 0, stream>>>(x, ctrl, pair_tok, Xg);
    gemm1_kernel<<<NMT * NT1, 256, 0, stream>>>(Xg, WgT, WuT, ctrl, G);
    gemm2_kernel<<<NMT * NT2 * 2, 256, 0, stream>>>(G, WdT, ctrl, Ya, Yb);
    combine_kernel<<<T_TOK, 192, 0, stream>>>(Ya, Yb, tok_pos, tok_w, out);
}